// Round 10
// baseline (202.793 us; speedup 1.0000x reference)
//
#include <hip/hip_runtime.h>
#include <cstdint>
#include <cstddef>

#define N_NODES_C 100000
#define NF 64      // feature width for both aggregations
#define BW 512     // bucket width (nodes)
#define NB 196     // ceil(100000/512)
#define CHUNK 8192 // edges per chunk block
#define SORT_CAP 9216

static inline size_t align256(size_t x) { return (x + 255) & ~size_t(255); }

typedef __attribute__((ext_vector_type(8))) short bf16x8;
typedef __attribute__((ext_vector_type(4))) float f32x4;

// bf16 helpers (RNE rounding)
__device__ inline float bf2f(unsigned short u) { return __uint_as_float(((unsigned)u) << 16); }
__device__ inline unsigned short f2bf(float x) {
    unsigned u = __float_as_uint(x);
    return (unsigned short)((u + 0x7fffu + ((u >> 16) & 1u)) >> 16);
}

// ---------- pass A: coarse bucket counts ----------
__global__ __launch_bounds__(1024) void bucket_count(const int* __restrict__ dst, int E,
                                                     int* __restrict__ counts) {
    __shared__ int hist[NB];
    int t = threadIdx.x;
    for (int i = t; i < NB; i += 1024) hist[i] = 0;
    __syncthreads();
    int e0 = blockIdx.x * CHUNK;
    int e1 = min(e0 + CHUNK, E);
    for (int e = e0 + t; e < e1; e += 1024) atomicAdd(&hist[dst[e] >> 9], 1);
    __syncthreads();
    for (int i = t; i < NB; i += 1024)
        if (hist[i]) atomicAdd(&counts[i], hist[i]);
}

// ---------- scan of 196 bucket counts (1 wave) ----------
__global__ void scan196(const int* __restrict__ counts, int* __restrict__ base196,
                        int* __restrict__ bucket_cursor, int* __restrict__ row_start, int n) {
    int lane = threadIdx.x;  // 64 threads
    int base = 0;
    for (int c = 0; c < NB; c += 64) {
        int idx = c + lane;
        int v = (idx < NB) ? counts[idx] : 0;
        int x = v;
        #pragma unroll
        for (int d = 1; d < 64; d <<= 1) {
            int y = __shfl_up(x, d, 64);
            if (lane >= d) x += y;
        }
        if (idx < NB) { base196[idx] = base + x - v; bucket_cursor[idx] = base + x - v; }
        base += __shfl(x, 63, 64);
    }
    if (lane == 0) { base196[NB] = base; row_start[n] = base; }
}

// ---------- pass B: coarse bucket binning, LDS-staged, coalesced output ----------
__global__ __launch_bounds__(1024) void bin_kernel(const int* __restrict__ src,
                                                   const int* __restrict__ dst, int E,
                                                   int* __restrict__ bucket_cursor,
                                                   int* __restrict__ packed) {
    __shared__ int hist[NB];
    __shared__ int lbase[NB];
    __shared__ int lcur[NB];
    __shared__ int gbase[NB];
    __shared__ int stage[CHUNK];
    __shared__ unsigned char bid[CHUNK];
    int t = threadIdx.x;
    int e0 = blockIdx.x * CHUNK;
    int e1 = min(e0 + CHUNK, E);
    for (int i = t; i < NB; i += 1024) hist[i] = 0;
    __syncthreads();
    for (int e = e0 + t; e < e1; e += 1024) atomicAdd(&hist[dst[e] >> 9], 1);
    __syncthreads();
    if (t < 64) {
        int base = 0;
        for (int c = 0; c < NB; c += 64) {
            int idx = c + t;
            int v = (idx < NB) ? hist[idx] : 0;
            int x = v;
            #pragma unroll
            for (int d = 1; d < 64; d <<= 1) {
                int y = __shfl_up(x, d, 64);
                if (t >= d) x += y;
            }
            if (idx < NB) { lbase[idx] = base + x - v; lcur[idx] = base + x - v; }
            base += __shfl(x, 63, 64);
        }
    }
    __syncthreads();
    if (t < NB) gbase[t] = atomicAdd(&bucket_cursor[t], hist[t]);
    for (int e = e0 + t; e < e1; e += 1024) {
        int d = dst[e];
        int b = d >> 9;
        int p = atomicAdd(&lcur[b], 1);
        stage[p] = (src[e] << 9) | (d & (BW - 1));
        bid[p] = (unsigned char)b;
    }
    __syncthreads();
    int cnt = e1 - e0;
    for (int i = t; i < cnt; i += 1024) {
        int b = bid[i];
        packed[gbase[b] + (i - lbase[b])] = stage[i];
    }
}

// ---------- pass C: per-bucket degree + row_start + dinv + counting sort ----------
__global__ __launch_bounds__(512) void bucket_sort_deg(const int* __restrict__ base196,
                                                       const int* __restrict__ packed,
                                                       int* __restrict__ sorted_src,
                                                       int* __restrict__ row_start,
                                                       float* __restrict__ dinv, int n) {
    __shared__ int hist[BW];
    __shared__ int cur[BW];
    __shared__ int wsum[8];
    __shared__ int sorted[SORT_CAP];
    int b = blockIdx.x;
    int node0 = b * BW;
    int nn = min(BW, n - node0);
    int base = base196[b];
    int end = base196[b + 1];
    int cnt = end - base;
    int t = threadIdx.x;
    hist[t] = 0;
    __syncthreads();
    for (int i = t; i < cnt; i += 512) atomicAdd(&hist[packed[base + i] & (BW - 1)], 1);
    __syncthreads();
    int v = hist[t];
    int lane = t & 63, w = t >> 6;
    int x = v;
    #pragma unroll
    for (int d = 1; d < 64; d <<= 1) {
        int y = __shfl_up(x, d, 64);
        if (lane >= d) x += y;
    }
    if (lane == 63) wsum[w] = x;
    __syncthreads();
    int woff = 0;
    for (int i = 0; i < w; ++i) woff += wsum[i];
    int excl = woff + x - v;
    cur[t] = excl;
    if (t < nn) {
        row_start[node0 + t] = base + excl;
        dinv[node0 + t] = rsqrtf((float)(v + 1));   // +1 self-loop
    }
    __syncthreads();
    for (int i = t; i < cnt; i += 512) {
        int pk = packed[base + i];
        int p = atomicAdd(&cur[pk & (BW - 1)], 1);
        sorted[p] = pk >> 9;
    }
    __syncthreads();
    for (int i = t; i < cnt; i += 512) sorted_src[base + i] = sorted[i];
}

// ---------- prep: weights -> bf16 MFMA B-fragment order ----------
// B-frag layout (16x16x32): col = lane&15, k = (lane>>4)*8 + j
__global__ __launch_bounds__(256) void prep_w(const float* __restrict__ W1,
                                              const float* __restrict__ W2,
                                              unsigned short* __restrict__ W1f,
                                              unsigned short* __restrict__ W2f) {
    int idx = blockIdx.x * 256 + threadIdx.x;   // grid 64 -> 16384
    int lane = (idx >> 3) & 63;
    int j = idx & 7;
    int kk = (lane >> 4) * 8 + j;
    int cb = lane & 15;
    if (idx < 8192) {
        int frag = idx >> 9;            // ct*2 + ks  (8 ct x 2 ks)
        int ct = frag >> 1, ks = frag & 1;
        W1f[idx] = f2bf(W1[(ks * 32 + kk) * 128 + ct * 16 + cb]);
    } else {
        int i2 = idx - 8192;
        int frag = i2 >> 9;             // ct*4 + ks  (4 ct x 4 ks)
        int ct = frag >> 2, ks = frag & 3;
        W2f[i2] = f2bf(W2[(ks * 32 + kk) * 64 + ct * 16 + cb]);
    }
}

// ---------- prescale: Xs[s] = bf16(dinv[s] * emb[s]) ----------
__global__ __launch_bounds__(256) void scale_emb(const float* __restrict__ emb,
                                                 const float* __restrict__ dinv,
                                                 unsigned short* __restrict__ Xs, int nq) {
    int q = blockIdx.x * 256 + threadIdx.x;
    if (q >= nq) return;
    int node = q >> 4;
    float d = dinv[node];
    float4 v = ((const float4*)emb)[q];
    ushort4 u;
    u.x = f2bf(v.x * d); u.y = f2bf(v.y * d);
    u.z = f2bf(v.z * d); u.w = f2bf(v.w * d);
    *(ushort4*)&Xs[(size_t)q * 4] = u;
}

// ---------- pull aggregation, HALF-ROW pass (32 features starting at foff) ----------
// out[i][foff..foff+31] = dinv[i] * ( sum_{s in N(i)} Xs[s] + Xs[i] ) + bias
// wave = 1 node; slot e = lane>>3 (8 slots x 4 edges = 32 edges/iter); c = lane&7 -> 4 feats.
// One gather instruction covers 8 edges (8 slots x 64B half-rows). Invalid -> zero pad row.
template<int OUTBF>
__global__ __launch_bounds__(256) void agg_half(const unsigned short* __restrict__ Xs,
                                                const float* __restrict__ dinv,
                                                const int* __restrict__ row_start,
                                                const int* __restrict__ sorted_src,
                                                const float* __restrict__ bias,
                                                void* __restrict__ outp, int n, int foff) {
    int lane = threadIdx.x & 63;
    int wid = threadIdx.x >> 6;
    int wave = blockIdx.x * (blockDim.x >> 6) + wid;
    int nwaves = gridDim.x * (blockDim.x >> 6);
    int e = lane >> 3;          // 8 edge slots
    int c = lane & 7;           // features foff+4c .. foff+4c+3
    int fo = foff + 4 * c;
    const int ZOFF = -64;       // element offset of the zeroed pad row
    for (int i = wave; i < n; i += nwaves) {
        int s0 = row_start[i], s1 = row_start[i + 1];
        float di = dinv[i];
        ushort4 uself = *(const ushort4*)&Xs[(size_t)i * NF + fo];
        float a0 = 0.f, a1 = 0.f, a2 = 0.f, a3 = 0.f;
        float g0 = 0.f, g1 = 0.f, g2 = 0.f, g3 = 0.f;
        for (int j = s0; j < s1; j += 32) {
            int b0 = j + 4 * e;
            int sj0 = b0, sj1 = b0 + 1, sj2 = b0 + 2, sj3 = b0 + 3;
            int i0 = sorted_src[min(sj0, s1 - 1)];
            int i1 = sorted_src[min(sj1, s1 - 1)];
            int i2 = sorted_src[min(sj2, s1 - 1)];
            int i3 = sorted_src[min(sj3, s1 - 1)];
            int o0 = (sj0 < s1) ? (i0 << 6) : ZOFF;
            int o1 = (sj1 < s1) ? (i1 << 6) : ZOFF;
            int o2 = (sj2 < s1) ? (i2 << 6) : ZOFF;
            int o3 = (sj3 < s1) ? (i3 << 6) : ZOFF;
            ushort4 u0 = *(const ushort4*)(Xs + o0 + fo);
            ushort4 u1 = *(const ushort4*)(Xs + o1 + fo);
            ushort4 u2 = *(const ushort4*)(Xs + o2 + fo);
            ushort4 u3 = *(const ushort4*)(Xs + o3 + fo);
            a0 += bf2f(u0.x); a1 += bf2f(u0.y); a2 += bf2f(u0.z); a3 += bf2f(u0.w);
            g0 += bf2f(u1.x); g1 += bf2f(u1.y); g2 += bf2f(u1.z); g3 += bf2f(u1.w);
            a0 += bf2f(u2.x); a1 += bf2f(u2.y); a2 += bf2f(u2.z); a3 += bf2f(u2.w);
            g0 += bf2f(u3.x); g1 += bf2f(u3.y); g2 += bf2f(u3.z); g3 += bf2f(u3.w);
        }
        a0 += g0; a1 += g1; a2 += g2; a3 += g3;
        a0 += __shfl_xor(a0, 8, 64);  a1 += __shfl_xor(a1, 8, 64);
        a2 += __shfl_xor(a2, 8, 64);  a3 += __shfl_xor(a3, 8, 64);
        a0 += __shfl_xor(a0, 16, 64); a1 += __shfl_xor(a1, 16, 64);
        a2 += __shfl_xor(a2, 16, 64); a3 += __shfl_xor(a3, 16, 64);
        a0 += __shfl_xor(a0, 32, 64); a1 += __shfl_xor(a1, 32, 64);
        a2 += __shfl_xor(a2, 32, 64); a3 += __shfl_xor(a3, 32, 64);
        if (e == 0) {
            a0 = di * (a0 + bf2f(uself.x));
            a1 = di * (a1 + bf2f(uself.y));
            a2 = di * (a2 + bf2f(uself.z));
            a3 = di * (a3 + bf2f(uself.w));
            if (bias) {
                float4 bb = *(const float4*)&bias[fo];
                a0 += bb.x; a1 += bb.y; a2 += bb.z; a3 += bb.w;
            }
            if constexpr (OUTBF) {
                unsigned short* out = (unsigned short*)outp;
                ushort4 o;
                o.x = f2bf(a0); o.y = f2bf(a1); o.z = f2bf(a2); o.w = f2bf(a3);
                *(ushort4*)&out[(size_t)i * NF + fo] = o;
            } else {
                float* out = (float*)outp;
                float4 o; o.x = a0; o.y = a1; o.z = a2; o.w = a3;
                *(float4*)&out[(size_t)i * NF + fo] = o;
            }
        }
    }
}

// ---------- MFMA fused GEMM: Tbf = bf16( dinv[row] * (relu(A@W1+b1) @ W2) ) ----------
__global__ __launch_bounds__(256) void gemm_mfma(const unsigned short* __restrict__ Abf,
                                                 const unsigned short* __restrict__ W1f,
                                                 const float* __restrict__ b1,
                                                 const unsigned short* __restrict__ W2f,
                                                 const float* __restrict__ dinv,
                                                 unsigned short* __restrict__ Tbf, int n) {
    __shared__ unsigned short h_all[4][16 * 136];
    const int t = threadIdx.x;
    const int wid = t >> 6, lane = t & 63;
    const int m = lane & 15, kg = lane >> 4;
    const int wrow = blockIdx.x * 64 + wid * 16;
    unsigned short* h_lds = h_all[wid];

    int arow = wrow + m; if (arow >= n) arow = n - 1;
    bf16x8 a0 = *(const bf16x8*)&Abf[(size_t)arow * 64 + kg * 8];
    bf16x8 a1 = *(const bf16x8*)&Abf[(size_t)arow * 64 + 32 + kg * 8];

    #pragma unroll
    for (int ct = 0; ct < 8; ++ct) {
        f32x4 acc = {0.f, 0.f, 0.f, 0.f};
        bf16x8 w0 = *(const bf16x8*)&W1f[(ct * 2 + 0) * 512 + lane * 8];
        bf16x8 w1 = *(const bf16x8*)&W1f[(ct * 2 + 1) * 512 + lane * 8];
        acc = __builtin_amdgcn_mfma_f32_16x16x32_bf16(a0, w0, acc, 0, 0, 0);
        acc = __builtin_amdgcn_mfma_f32_16x16x32_bf16(a1, w1, acc, 0, 0, 0);
        float bb = b1[ct * 16 + m];
        #pragma unroll
        for (int r = 0; r < 4; ++r) {
            float v = fmaxf(acc[r] + bb, 0.f);
            h_lds[(kg * 4 + r) * 136 + ct * 16 + m] = f2bf(v);
        }
    }

    bf16x8 hf[4];
    #pragma unroll
    for (int ks = 0; ks < 4; ++ks)
        hf[ks] = *(const bf16x8*)&h_lds[m * 136 + ks * 32 + kg * 8];

    float dv[4];
    #pragma unroll
    for (int r = 0; r < 4; ++r) {
        int row = wrow + kg * 4 + r;
        dv[r] = (row < n) ? dinv[row] : 0.f;
    }
    #pragma unroll
    for (int ct = 0; ct < 4; ++ct) {
        f32x4 acc = {0.f, 0.f, 0.f, 0.f};
        #pragma unroll
        for (int ks = 0; ks < 4; ++ks) {
            bf16x8 w = *(const bf16x8*)&W2f[(ct * 4 + ks) * 512 + lane * 8];
            acc = __builtin_amdgcn_mfma_f32_16x16x32_bf16(hf[ks], w, acc, 0, 0, 0);
        }
        #pragma unroll
        for (int r = 0; r < 4; ++r) {
            int row = wrow + kg * 4 + r;
            if (row < n) Tbf[(size_t)row * 64 + ct * 16 + m] = f2bf(acc[r] * dv[r]);
        }
    }
}

extern "C" void kernel_launch(void* const* d_in, const int* in_sizes, int n_in,
                              void* d_out, int out_size, void* d_ws, size_t ws_size,
                              hipStream_t stream) {
    const int* edge = (const int*)d_in[0];       // int32 (JAX x64 disabled)
    const float* emb = (const float*)d_in[1];
    const float* W1  = (const float*)d_in[2];
    const float* b1  = (const float*)d_in[3];
    const float* W2  = (const float*)d_in[4];
    const float* b2  = (const float*)d_in[5];
    int E = in_sizes[0] / 2;
    const int* src = edge;
    const int* dst = edge + E;
    int n = N_NODES_C;

    char* p = (char*)d_ws;
    int*   row_start  = (int*)p;   p += align256((size_t)(n + 1) * 4);
    float* dinv       = (float*)p; p += align256((size_t)n * 4);
    int*   bcounts    = (int*)p;   p += align256(256 * 4);
    int*   base196    = (int*)p;   p += align256(256 * 4);
    int*   bucket_cur = (int*)p;   p += align256(256 * 4);
    unsigned short* W1f = (unsigned short*)p; p += align256(8192 * 2);
    unsigned short* W2f = (unsigned short*)p; p += align256(8192 * 2);
    int*   sorted_src = (int*)p;   p += align256((size_t)E * 4);
    char*  zpadA      = p;         p += 256;   // zero pad row for Abf
    unsigned short* Abf = (unsigned short*)p; p += align256((size_t)n * NF * 2);
    char*  zpadX      = p;         p += 256;   // zero pad row for Xs
    unsigned short* Xs  = (unsigned short*)p; p += align256((size_t)n * NF * 2);
    // packed aliases Abf: its lifetime [bin_kernel, bucket_sort_deg] ends before Abf is written
    int* packed = (int*)Abf;

    prep_w<<<64, 256, 0, stream>>>(W1, W2, W1f, W2f);
    hipMemsetAsync(bcounts, 0, NB * 4, stream);
    hipMemsetAsync(zpadA, 0, 256, stream);
    hipMemsetAsync(zpadX, 0, 256, stream);
    int nbin = (E + CHUNK - 1) / CHUNK;
    bucket_count<<<nbin, 1024, 0, stream>>>(dst, E, bcounts);
    scan196<<<1, 64, 0, stream>>>(bcounts, base196, bucket_cur, row_start, n);
    bin_kernel<<<nbin, 1024, 0, stream>>>(src, dst, E, bucket_cur, packed);
    bucket_sort_deg<<<NB, 512, 0, stream>>>(base196, packed, sorted_src, row_start, dinv, n);

    // prescale emb by dinv into bf16
    int nq = n * 16;
    scale_emb<<<(nq + 255) / 256, 256, 0, stream>>>(emb, dinv, Xs, nq);
    // layer 1 aggregation -> Abf (bf16), two half-row passes (6.4 MB working set each)
    agg_half<1><<<4096, 256, 0, stream>>>(Xs, dinv, row_start, sorted_src, nullptr, Abf, n, 0);
    agg_half<1><<<4096, 256, 0, stream>>>(Xs, dinv, row_start, sorted_src, nullptr, Abf, n, 32);
    // fused MFMA GEMM: Xs <- bf16( dinv * (relu(Abf@W1+b1)@W2) )
    gemm_mfma<<<(n + 63) / 64, 256, 0, stream>>>(Abf, W1f, b1, W2f, dinv, Xs, n);
    // layer 2 aggregation + b2 -> out (f32), two half-row passes
    agg_half<0><<<4096, 256, 0, stream>>>(Xs, dinv, row_start, sorted_src, b2, d_out, n, 0);
    agg_half<0><<<4096, 256, 0, stream>>>(Xs, dinv, row_start, sorted_src, b2, d_out, n, 32);
}

// Round 11
// 140.580 us; speedup vs baseline: 1.4425x; 1.4425x over previous
//
#include <hip/hip_runtime.h>
#include <cstdint>
#include <cstddef>

#define N_NODES_C 100000
#define NF 64      // feature width for both aggregations
#define BW 512     // bucket width (nodes)
#define NB 196     // ceil(100000/512)
#define CHUNK 8192 // edges per chunk block
#define SORT_CAP 9216

static inline size_t align256(size_t x) { return (x + 255) & ~size_t(255); }

typedef __attribute__((ext_vector_type(8))) short bf16x8;
typedef __attribute__((ext_vector_type(4))) float f32x4;

// bf16 helpers (RNE rounding)
__device__ inline float bf2f(unsigned short u) { return __uint_as_float(((unsigned)u) << 16); }
__device__ inline unsigned short f2bf(float x) {
    unsigned u = __float_as_uint(x);
    return (unsigned short)((u + 0x7fffu + ((u >> 16) & 1u)) >> 16);
}

// ---------- pass A: per-chunk bucket histograms (stored, reused by bin pass) ----------
__global__ __launch_bounds__(1024) void count_hist(const int* __restrict__ dst, int E,
                                                   int* __restrict__ chunk_hist) {
    __shared__ int hist[NB];
    int t = threadIdx.x;
    for (int i = t; i < NB; i += 1024) hist[i] = 0;
    __syncthreads();
    int e0 = blockIdx.x * CHUNK;
    int e1 = min(e0 + CHUNK, E);
    for (int e = e0 + t; e < e1; e += 1024) atomicAdd(&hist[dst[e] >> 9], 1);
    __syncthreads();
    for (int i = t; i < NB; i += 1024) chunk_hist[blockIdx.x * NB + i] = hist[i];
}

// ---------- per-bucket exclusive scan across chunks: gpart[c][b], colsum[b] ----------
__global__ void scan_cols(const int* __restrict__ chunk_hist, int nbin,
                          int* __restrict__ gpart, int* __restrict__ colsum) {
    int b = blockIdx.x;          // bucket
    int lane = threadIdx.x;      // 64 threads
    int base = 0;
    for (int c0 = 0; c0 < nbin; c0 += 64) {
        int c = c0 + lane;
        int v = (c < nbin) ? chunk_hist[c * NB + b] : 0;
        int x = v;
        #pragma unroll
        for (int d = 1; d < 64; d <<= 1) {
            int y = __shfl_up(x, d, 64);
            if (lane >= d) x += y;
        }
        if (c < nbin) gpart[c * NB + b] = base + x - v;
        base += __shfl(x, 63, 64);
    }
    if (lane == 0) colsum[b] = base;
}

// ---------- scan of 196 bucket totals (1 wave) + pad zeroing ----------
__global__ void scan196b(const int* __restrict__ colsum, int* __restrict__ base196,
                         int* __restrict__ row_start, int n,
                         int* __restrict__ zpadA, int* __restrict__ zpadX) {
    int lane = threadIdx.x;  // 64 threads
    zpadA[lane] = 0;         // 256B pad rows (64 ints each)
    zpadX[lane] = 0;
    int base = 0;
    for (int c = 0; c < NB; c += 64) {
        int idx = c + lane;
        int v = (idx < NB) ? colsum[idx] : 0;
        int x = v;
        #pragma unroll
        for (int d = 1; d < 64; d <<= 1) {
            int y = __shfl_up(x, d, 64);
            if (lane >= d) x += y;
        }
        if (idx < NB) base196[idx] = base + x - v;
        base += __shfl(x, 63, 64);
    }
    if (lane == 0) { base196[NB] = base; row_start[n] = base; }
}

// ---------- pass B: bucket binning using precomputed hists/bases (no atomic cursors) ----------
// packed entry = (src << 9) | (dst & 511); bucket = dst >> 9
__global__ __launch_bounds__(1024) void bin_kernel2(const int* __restrict__ src,
                                                    const int* __restrict__ dst, int E,
                                                    const int* __restrict__ chunk_hist,
                                                    const int* __restrict__ gpart,
                                                    const int* __restrict__ base196,
                                                    int* __restrict__ packed) {
    __shared__ int hist[NB];
    __shared__ int lbase[NB];
    __shared__ int lcur[NB];
    __shared__ int dbase[NB];
    __shared__ int stage[CHUNK];
    __shared__ unsigned char bid[CHUNK];
    int t = threadIdx.x;
    int ch = blockIdx.x;
    int e0 = ch * CHUNK;
    int e1 = min(e0 + CHUNK, E);
    for (int i = t; i < NB; i += 1024) {
        hist[i] = chunk_hist[ch * NB + i];
        dbase[i] = base196[i] + gpart[ch * NB + i];
    }
    __syncthreads();
    if (t < 64) {
        int base = 0;
        for (int c = 0; c < NB; c += 64) {
            int idx = c + t;
            int v = (idx < NB) ? hist[idx] : 0;
            int x = v;
            #pragma unroll
            for (int d = 1; d < 64; d <<= 1) {
                int y = __shfl_up(x, d, 64);
                if (t >= d) x += y;
            }
            if (idx < NB) { lbase[idx] = base + x - v; lcur[idx] = base + x - v; }
            base += __shfl(x, 63, 64);
        }
    }
    __syncthreads();
    for (int e = e0 + t; e < e1; e += 1024) {
        int d = dst[e];
        int b = d >> 9;
        int p = atomicAdd(&lcur[b], 1);
        stage[p] = (src[e] << 9) | (d & (BW - 1));
        bid[p] = (unsigned char)b;
    }
    __syncthreads();
    int cnt = e1 - e0;
    for (int i = t; i < cnt; i += 1024) {
        int b = bid[i];
        packed[dbase[b] + (i - lbase[b])] = stage[i];
    }
}

// ---------- pass C: per-bucket degree + row_start + dinv + counting sort ----------
__global__ __launch_bounds__(512) void bucket_sort_deg(const int* __restrict__ base196,
                                                       const int* __restrict__ packed,
                                                       int* __restrict__ sorted_src,
                                                       int* __restrict__ row_start,
                                                       float* __restrict__ dinv, int n) {
    __shared__ int hist[BW];
    __shared__ int cur[BW];
    __shared__ int wsum[8];
    __shared__ int sorted[SORT_CAP];
    int b = blockIdx.x;
    int node0 = b * BW;
    int nn = min(BW, n - node0);
    int base = base196[b];
    int end = base196[b + 1];
    int cnt = end - base;
    int t = threadIdx.x;
    hist[t] = 0;
    __syncthreads();
    for (int i = t; i < cnt; i += 512) atomicAdd(&hist[packed[base + i] & (BW - 1)], 1);
    __syncthreads();
    int v = hist[t];
    int lane = t & 63, w = t >> 6;
    int x = v;
    #pragma unroll
    for (int d = 1; d < 64; d <<= 1) {
        int y = __shfl_up(x, d, 64);
        if (lane >= d) x += y;
    }
    if (lane == 63) wsum[w] = x;
    __syncthreads();
    int woff = 0;
    for (int i = 0; i < w; ++i) woff += wsum[i];
    int excl = woff + x - v;
    cur[t] = excl;
    if (t < nn) {
        row_start[node0 + t] = base + excl;
        dinv[node0 + t] = rsqrtf((float)(v + 1));   // +1 self-loop
    }
    __syncthreads();
    for (int i = t; i < cnt; i += 512) {
        int pk = packed[base + i];
        int p = atomicAdd(&cur[pk & (BW - 1)], 1);
        sorted[p] = pk >> 9;
    }
    __syncthreads();
    for (int i = t; i < cnt; i += 512) sorted_src[base + i] = sorted[i];
}

// ---------- prep: weights -> bf16 MFMA B-fragment order ----------
// B-frag layout (16x16x32): col = lane&15, k = (lane>>4)*8 + j
__global__ __launch_bounds__(256) void prep_w(const float* __restrict__ W1,
                                              const float* __restrict__ W2,
                                              unsigned short* __restrict__ W1f,
                                              unsigned short* __restrict__ W2f) {
    int idx = blockIdx.x * 256 + threadIdx.x;   // grid 64 -> 16384
    int lane = (idx >> 3) & 63;
    int j = idx & 7;
    int kk = (lane >> 4) * 8 + j;
    int cb = lane & 15;
    if (idx < 8192) {
        int frag = idx >> 9;            // ct*2 + ks  (8 ct x 2 ks)
        int ct = frag >> 1, ks = frag & 1;
        W1f[idx] = f2bf(W1[(ks * 32 + kk) * 128 + ct * 16 + cb]);
    } else {
        int i2 = idx - 8192;
        int frag = i2 >> 9;             // ct*4 + ks  (4 ct x 4 ks)
        int ct = frag >> 2, ks = frag & 3;
        W2f[i2] = f2bf(W2[(ks * 32 + kk) * 64 + ct * 16 + cb]);
    }
}

// ---------- prescale: Xs[s] = bf16(dinv[s] * emb[s]) ----------
__global__ __launch_bounds__(256) void scale_emb(const float* __restrict__ emb,
                                                 const float* __restrict__ dinv,
                                                 unsigned short* __restrict__ Xs, int nq) {
    int q = blockIdx.x * 256 + threadIdx.x;
    if (q >= nq) return;
    int node = q >> 4;
    float d = dinv[node];
    float4 v = ((const float4*)emb)[q];
    ushort4 u;
    u.x = f2bf(v.x * d); u.y = f2bf(v.y * d);
    u.z = f2bf(v.z * d); u.w = f2bf(v.w * d);
    *(ushort4*)&Xs[(size_t)q * 4] = u;
}

// ---------- pull aggregation over pre-scaled bf16 rows (round-9 version) ----------
// out[i] = dinv[i] * ( sum_{s in N(i)} Xs[s] + Xs[i] ) + bias
// wave = 1 node; slot e = lane>>4 handles edges j+4e..j+4e+3; c = lane&15 -> features 4c..4c+3.
// Single fully-masked 16-edge loop: invalid lanes gather the zeroed pad row at Xs[-64].
template<int OUTBF>
__global__ __launch_bounds__(256) void agg_bf16(const unsigned short* __restrict__ Xs,
                                                const float* __restrict__ dinv,
                                                const int* __restrict__ row_start,
                                                const int* __restrict__ sorted_src,
                                                const float* __restrict__ bias,
                                                void* __restrict__ outp, int n) {
    int lane = threadIdx.x & 63;
    int wid = threadIdx.x >> 6;
    int wave = blockIdx.x * (blockDim.x >> 6) + wid;
    int nwaves = gridDim.x * (blockDim.x >> 6);
    int e = lane >> 4;
    int c = lane & 15;
    const int ZOFF = -64;   // element offset of the zeroed pad row
    for (int i = wave; i < n; i += nwaves) {
        int s0 = row_start[i], s1 = row_start[i + 1];
        float di = dinv[i];
        ushort4 uself = *(const ushort4*)&Xs[(size_t)i * NF + 4 * c];
        float a0 = 0.f, a1 = 0.f, a2 = 0.f, a3 = 0.f;
        float g0 = 0.f, g1 = 0.f, g2 = 0.f, g3 = 0.f;
        for (int j = s0; j < s1; j += 16) {
            int b0 = j + 4 * e;
            int sj0 = b0, sj1 = b0 + 1, sj2 = b0 + 2, sj3 = b0 + 3;
            int i0 = sorted_src[min(sj0, s1 - 1)];
            int i1 = sorted_src[min(sj1, s1 - 1)];
            int i2 = sorted_src[min(sj2, s1 - 1)];
            int i3 = sorted_src[min(sj3, s1 - 1)];
            int o0 = (sj0 < s1) ? (i0 << 6) : ZOFF;
            int o1 = (sj1 < s1) ? (i1 << 6) : ZOFF;
            int o2 = (sj2 < s1) ? (i2 << 6) : ZOFF;
            int o3 = (sj3 < s1) ? (i3 << 6) : ZOFF;
            ushort4 u0 = *(const ushort4*)(Xs + o0 + 4 * c);
            ushort4 u1 = *(const ushort4*)(Xs + o1 + 4 * c);
            ushort4 u2 = *(const ushort4*)(Xs + o2 + 4 * c);
            ushort4 u3 = *(const ushort4*)(Xs + o3 + 4 * c);
            a0 += bf2f(u0.x); a1 += bf2f(u0.y); a2 += bf2f(u0.z); a3 += bf2f(u0.w);
            g0 += bf2f(u1.x); g1 += bf2f(u1.y); g2 += bf2f(u1.z); g3 += bf2f(u1.w);
            a0 += bf2f(u2.x); a1 += bf2f(u2.y); a2 += bf2f(u2.z); a3 += bf2f(u2.w);
            g0 += bf2f(u3.x); g1 += bf2f(u3.y); g2 += bf2f(u3.z); g3 += bf2f(u3.w);
        }
        a0 += g0; a1 += g1; a2 += g2; a3 += g3;
        a0 += __shfl_xor(a0, 16, 64); a1 += __shfl_xor(a1, 16, 64);
        a2 += __shfl_xor(a2, 16, 64); a3 += __shfl_xor(a3, 16, 64);
        a0 += __shfl_xor(a0, 32, 64); a1 += __shfl_xor(a1, 32, 64);
        a2 += __shfl_xor(a2, 32, 64); a3 += __shfl_xor(a3, 32, 64);
        if (e == 0) {
            a0 = di * (a0 + bf2f(uself.x));
            a1 = di * (a1 + bf2f(uself.y));
            a2 = di * (a2 + bf2f(uself.z));
            a3 = di * (a3 + bf2f(uself.w));
            if (bias) {
                float4 bb = *(const float4*)&bias[4 * c];
                a0 += bb.x; a1 += bb.y; a2 += bb.z; a3 += bb.w;
            }
            if constexpr (OUTBF) {
                unsigned short* out = (unsigned short*)outp;
                ushort4 o;
                o.x = f2bf(a0); o.y = f2bf(a1); o.z = f2bf(a2); o.w = f2bf(a3);
                *(ushort4*)&out[(size_t)i * NF + 4 * c] = o;
            } else {
                float* out = (float*)outp;
                float4 o; o.x = a0; o.y = a1; o.z = a2; o.w = a3;
                *(float4*)&out[(size_t)i * NF + 4 * c] = o;
            }
        }
    }
}

// ---------- MFMA fused GEMM: Tbf = bf16( dinv[row] * (relu(A@W1+b1) @ W2) ) ----------
__global__ __launch_bounds__(256) void gemm_mfma(const unsigned short* __restrict__ Abf,
                                                 const unsigned short* __restrict__ W1f,
                                                 const float* __restrict__ b1,
                                                 const unsigned short* __restrict__ W2f,
                                                 const float* __restrict__ dinv,
                                                 unsigned short* __restrict__ Tbf, int n) {
    __shared__ unsigned short h_all[4][16 * 136];
    const int t = threadIdx.x;
    const int wid = t >> 6, lane = t & 63;
    const int m = lane & 15, kg = lane >> 4;
    const int wrow = blockIdx.x * 64 + wid * 16;
    unsigned short* h_lds = h_all[wid];

    int arow = wrow + m; if (arow >= n) arow = n - 1;
    bf16x8 a0 = *(const bf16x8*)&Abf[(size_t)arow * 64 + kg * 8];
    bf16x8 a1 = *(const bf16x8*)&Abf[(size_t)arow * 64 + 32 + kg * 8];

    #pragma unroll
    for (int ct = 0; ct < 8; ++ct) {
        f32x4 acc = {0.f, 0.f, 0.f, 0.f};
        bf16x8 w0 = *(const bf16x8*)&W1f[(ct * 2 + 0) * 512 + lane * 8];
        bf16x8 w1 = *(const bf16x8*)&W1f[(ct * 2 + 1) * 512 + lane * 8];
        acc = __builtin_amdgcn_mfma_f32_16x16x32_bf16(a0, w0, acc, 0, 0, 0);
        acc = __builtin_amdgcn_mfma_f32_16x16x32_bf16(a1, w1, acc, 0, 0, 0);
        float bb = b1[ct * 16 + m];
        #pragma unroll
        for (int r = 0; r < 4; ++r) {
            float v = fmaxf(acc[r] + bb, 0.f);
            h_lds[(kg * 4 + r) * 136 + ct * 16 + m] = f2bf(v);
        }
    }

    bf16x8 hf[4];
    #pragma unroll
    for (int ks = 0; ks < 4; ++ks)
        hf[ks] = *(const bf16x8*)&h_lds[m * 136 + ks * 32 + kg * 8];

    float dv[4];
    #pragma unroll
    for (int r = 0; r < 4; ++r) {
        int row = wrow + kg * 4 + r;
        dv[r] = (row < n) ? dinv[row] : 0.f;
    }
    #pragma unroll
    for (int ct = 0; ct < 4; ++ct) {
        f32x4 acc = {0.f, 0.f, 0.f, 0.f};
        #pragma unroll
        for (int ks = 0; ks < 4; ++ks) {
            bf16x8 w = *(const bf16x8*)&W2f[(ct * 4 + ks) * 512 + lane * 8];
            acc = __builtin_amdgcn_mfma_f32_16x16x32_bf16(hf[ks], w, acc, 0, 0, 0);
        }
        #pragma unroll
        for (int r = 0; r < 4; ++r) {
            int row = wrow + kg * 4 + r;
            if (row < n) Tbf[(size_t)row * 64 + ct * 16 + m] = f2bf(acc[r] * dv[r]);
        }
    }
}

extern "C" void kernel_launch(void* const* d_in, const int* in_sizes, int n_in,
                              void* d_out, int out_size, void* d_ws, size_t ws_size,
                              hipStream_t stream) {
    const int* edge = (const int*)d_in[0];       // int32 (JAX x64 disabled)
    const float* emb = (const float*)d_in[1];
    const float* W1  = (const float*)d_in[2];
    const float* b1  = (const float*)d_in[3];
    const float* W2  = (const float*)d_in[4];
    const float* b2  = (const float*)d_in[5];
    int E = in_sizes[0] / 2;
    const int* src = edge;
    const int* dst = edge + E;
    int n = N_NODES_C;
    int nbin = (E + CHUNK - 1) / CHUNK;

    char* p = (char*)d_ws;
    int*   row_start  = (int*)p;   p += align256((size_t)(n + 1) * 4);
    float* dinv       = (float*)p; p += align256((size_t)n * 4);
    int*   base196    = (int*)p;   p += align256(256 * 4);
    int*   colsum     = (int*)p;   p += align256(256 * 4);
    int*   chunk_hist = (int*)p;   p += align256((size_t)nbin * NB * 4);
    int*   gpart      = (int*)p;   p += align256((size_t)nbin * NB * 4);
    unsigned short* W1f = (unsigned short*)p; p += align256(8192 * 2);
    unsigned short* W2f = (unsigned short*)p; p += align256(8192 * 2);
    int*   sorted_src = (int*)p;   p += align256((size_t)E * 4);
    int*   zpadA      = (int*)p;   p += 256;   // zero pad row for Abf
    unsigned short* Abf = (unsigned short*)p; p += align256((size_t)n * NF * 2);
    int*   zpadX      = (int*)p;   p += 256;   // zero pad row for Xs
    unsigned short* Xs  = (unsigned short*)p; p += align256((size_t)n * NF * 2);
    // packed aliases Abf: its lifetime [bin_kernel2, bucket_sort_deg] ends before Abf is written
    int* packed = (int*)Abf;

    prep_w<<<64, 256, 0, stream>>>(W1, W2, W1f, W2f);
    count_hist<<<nbin, 1024, 0, stream>>>(dst, E, chunk_hist);
    scan_cols<<<NB, 64, 0, stream>>>(chunk_hist, nbin, gpart, colsum);
    scan196b<<<1, 64, 0, stream>>>(colsum, base196, row_start, n, zpadA, zpadX);
    bin_kernel2<<<nbin, 1024, 0, stream>>>(src, dst, E, chunk_hist, gpart, base196, packed);
    bucket_sort_deg<<<NB, 512, 0, stream>>>(base196, packed, sorted_src, row_start, dinv, n);

    // prescale emb by dinv into bf16
    int nq = n * 16;
    scale_emb<<<(nq + 255) / 256, 256, 0, stream>>>(emb, dinv, Xs, nq);
    // layer 1 aggregation -> Abf (bf16)
    agg_bf16<1><<<4096, 256, 0, stream>>>(Xs, dinv, row_start, sorted_src, nullptr, Abf, n);
    // fused MFMA GEMM: Xs <- bf16( dinv * (relu(Abf@W1+b1)@W2) )
    gemm_mfma<<<(n + 63) / 64, 256, 0, stream>>>(Abf, W1f, b1, W2f, dinv, Xs, n);
    // layer 2 aggregation + b2 -> out (f32)
    agg_bf16<0><<<4096, 256, 0, stream>>>(Xs, dinv, row_start, sorted_src, b2, d_out, n);
}

// Round 12
// 137.318 us; speedup vs baseline: 1.4768x; 1.0238x over previous
//
#include <hip/hip_runtime.h>
#include <cstdint>
#include <cstddef>

#define N_NODES_C 100000
#define NF 64      // feature width for both aggregations
#define BW 512     // bucket width (nodes)
#define NB 196     // ceil(100000/512)
#define CHUNK 8192 // edges per chunk block
#define SORT_CAP 9216

static inline size_t align256(size_t x) { return (x + 255) & ~size_t(255); }

typedef __attribute__((ext_vector_type(8))) short bf16x8;
typedef __attribute__((ext_vector_type(4))) float f32x4;

// bf16 helpers (RNE rounding)
__device__ inline float bf2f(unsigned short u) { return __uint_as_float(((unsigned)u) << 16); }
__device__ inline unsigned short f2bf(float x) {
    unsigned u = __float_as_uint(x);
    return (unsigned short)((u + 0x7fffu + ((u >> 16) & 1u)) >> 16);
}

// ---------- pass A: per-chunk bucket histograms + fused weight prep ----------
// B-frag layout (16x16x32): col = lane&15, k = (lane>>4)*8 + j
__global__ __launch_bounds__(1024) void count_hist(const int* __restrict__ dst, int E,
                                                   int* __restrict__ chunk_hist,
                                                   const float* __restrict__ W1,
                                                   const float* __restrict__ W2,
                                                   unsigned short* __restrict__ W1f,
                                                   unsigned short* __restrict__ W2f,
                                                   int* __restrict__ done_ctr) {
    __shared__ int hist[NB];
    int t = threadIdx.x;
    if (blockIdx.x == 0 && t == 0) *done_ctr = 0;
    // fused prep_w: blocks 0..15 cover idx 0..16383
    int idx = blockIdx.x * 1024 + t;
    if (idx < 16384) {
        int lane = (idx >> 3) & 63;
        int j = idx & 7;
        int kk = (lane >> 4) * 8 + j;
        int cb = lane & 15;
        if (idx < 8192) {
            int frag = idx >> 9;            // ct*2 + ks  (8 ct x 2 ks)
            int ct = frag >> 1, ks = frag & 1;
            W1f[idx] = f2bf(W1[(ks * 32 + kk) * 128 + ct * 16 + cb]);
        } else {
            int i2 = idx - 8192;
            int frag = i2 >> 9;             // ct*4 + ks  (4 ct x 4 ks)
            int ct = frag >> 2, ks = frag & 3;
            W2f[i2] = f2bf(W2[(ks * 32 + kk) * 64 + ct * 16 + cb]);
        }
    }
    for (int i = t; i < NB; i += 1024) hist[i] = 0;
    __syncthreads();
    int e0 = blockIdx.x * CHUNK;
    int e1 = min(e0 + CHUNK, E);
    for (int e = e0 + t; e < e1; e += 1024) atomicAdd(&hist[dst[e] >> 9], 1);
    __syncthreads();
    for (int i = t; i < NB; i += 1024) chunk_hist[blockIdx.x * NB + i] = hist[i];
}

// ---------- per-bucket exclusive scan across chunks + tail-block global scan ----------
__global__ void scan_cols(const int* __restrict__ chunk_hist, int nbin,
                          int* __restrict__ gpart, int* __restrict__ colsum,
                          int* __restrict__ base196, int* __restrict__ row_start, int n,
                          int* __restrict__ zpadA, int* __restrict__ zpadX,
                          int* __restrict__ done_ctr) {
    int b = blockIdx.x;          // bucket
    int lane = threadIdx.x;      // 64 threads
    int base = 0;
    for (int c0 = 0; c0 < nbin; c0 += 64) {
        int c = c0 + lane;
        int v = (c < nbin) ? chunk_hist[c * NB + b] : 0;
        int x = v;
        #pragma unroll
        for (int d = 1; d < 64; d <<= 1) {
            int y = __shfl_up(x, d, 64);
            if (lane >= d) x += y;
        }
        if (c < nbin) gpart[c * NB + b] = base + x - v;
        base += __shfl(x, 63, 64);
    }
    if (lane == 0) colsum[b] = base;
    __threadfence();
    __shared__ int amlast;
    if (lane == 0) amlast = (atomicAdd(done_ctr, 1) == NB - 1) ? 1 : 0;
    __syncthreads();
    if (amlast) {
        // last block: scan the 196 bucket totals, zero pad rows
        zpadA[lane] = 0;
        zpadX[lane] = 0;
        volatile const int* vcs = colsum;   // bypass L1: other blocks' writes
        int bb = 0;
        for (int c = 0; c < NB; c += 64) {
            int idx2 = c + lane;
            int v = (idx2 < NB) ? vcs[idx2] : 0;
            int x = v;
            #pragma unroll
            for (int d = 1; d < 64; d <<= 1) {
                int y = __shfl_up(x, d, 64);
                if (lane >= d) x += y;
            }
            if (idx2 < NB) base196[idx2] = bb + x - v;
            bb += __shfl(x, 63, 64);
        }
        if (lane == 0) { base196[NB] = bb; row_start[n] = bb; }
    }
}

// ---------- pass B: bucket binning using precomputed hists/bases ----------
// packed entry = (src << 9) | (dst & 511); bucket = dst >> 9
__global__ __launch_bounds__(1024) void bin_kernel2(const int* __restrict__ src,
                                                    const int* __restrict__ dst, int E,
                                                    const int* __restrict__ chunk_hist,
                                                    const int* __restrict__ gpart,
                                                    const int* __restrict__ base196,
                                                    int* __restrict__ packed) {
    __shared__ int hist[NB];
    __shared__ int lbase[NB];
    __shared__ int lcur[NB];
    __shared__ int dbase[NB];
    __shared__ int stage[CHUNK];
    __shared__ unsigned char bid[CHUNK];
    int t = threadIdx.x;
    int ch = blockIdx.x;
    int e0 = ch * CHUNK;
    int e1 = min(e0 + CHUNK, E);
    for (int i = t; i < NB; i += 1024) {
        hist[i] = chunk_hist[ch * NB + i];
        dbase[i] = base196[i] + gpart[ch * NB + i];
    }
    __syncthreads();
    if (t < 64) {
        int base = 0;
        for (int c = 0; c < NB; c += 64) {
            int idx = c + t;
            int v = (idx < NB) ? hist[idx] : 0;
            int x = v;
            #pragma unroll
            for (int d = 1; d < 64; d <<= 1) {
                int y = __shfl_up(x, d, 64);
                if (t >= d) x += y;
            }
            if (idx < NB) { lbase[idx] = base + x - v; lcur[idx] = base + x - v; }
            base += __shfl(x, 63, 64);
        }
    }
    __syncthreads();
    for (int e = e0 + t; e < e1; e += 1024) {
        int d = dst[e];
        int b = d >> 9;
        int p = atomicAdd(&lcur[b], 1);
        stage[p] = (src[e] << 9) | (d & (BW - 1));
        bid[p] = (unsigned char)b;
    }
    __syncthreads();
    int cnt = e1 - e0;
    for (int i = t; i < cnt; i += 1024) {
        int b = bid[i];
        packed[dbase[b] + (i - lbase[b])] = stage[i];
    }
}

// ---------- pass C: degree + row_start + dinv + counting sort + fused emb prescale ----------
__global__ __launch_bounds__(1024) void bucket_sort_deg(const int* __restrict__ base196,
                                                        const int* __restrict__ packed,
                                                        int* __restrict__ sorted_src,
                                                        int* __restrict__ row_start,
                                                        float* __restrict__ dinv,
                                                        const float* __restrict__ emb,
                                                        unsigned short* __restrict__ Xs, int n) {
    __shared__ int hist[BW];
    __shared__ int cur[BW];
    __shared__ float dloc[BW];
    __shared__ int wsum[8];
    __shared__ int sorted[SORT_CAP];
    int b = blockIdx.x;
    int node0 = b * BW;
    int nn = min(BW, n - node0);
    int base = base196[b];
    int end = base196[b + 1];
    int cnt = end - base;
    int t = threadIdx.x;
    int lane = t & 63, w = t >> 6;
    if (t < BW) hist[t] = 0;
    __syncthreads();
    for (int i = t; i < cnt; i += 1024) atomicAdd(&hist[packed[base + i] & (BW - 1)], 1);
    __syncthreads();
    int v = 0, x = 0;
    if (t < BW) {                       // waves 0-7, fully active
        v = hist[t];
        x = v;
        #pragma unroll
        for (int d = 1; d < 64; d <<= 1) {
            int y = __shfl_up(x, d, 64);
            if (lane >= d) x += y;
        }
        if (lane == 63) wsum[w] = x;
    }
    __syncthreads();
    if (t < BW) {
        int woff = 0;
        for (int i = 0; i < w; ++i) woff += wsum[i];
        int excl = woff + x - v;
        cur[t] = excl;
        float dv_ = rsqrtf((float)(v + 1));   // +1 self-loop
        dloc[t] = dv_;
        if (t < nn) {
            row_start[node0 + t] = base + excl;
            dinv[node0 + t] = dv_;
        }
    }
    __syncthreads();
    for (int i = t; i < cnt; i += 1024) {
        int pk = packed[base + i];
        int p = atomicAdd(&cur[pk & (BW - 1)], 1);
        sorted[p] = pk >> 9;
    }
    __syncthreads();
    for (int i = t; i < cnt; i += 1024) sorted_src[base + i] = sorted[i];
    // fused prescale: Xs[node] = bf16(dinv[node] * emb[node]) for this bucket's rows
    int nq = nn * 16;                   // float4 units
    for (int q = t; q < nq; q += 1024) {
        int node = node0 + (q >> 4);
        float d = dloc[q >> 4];
        float4 vv = *(const float4*)&emb[(size_t)node * 64 + (q & 15) * 4];
        ushort4 u;
        u.x = f2bf(vv.x * d); u.y = f2bf(vv.y * d);
        u.z = f2bf(vv.z * d); u.w = f2bf(vv.w * d);
        *(ushort4*)&Xs[(size_t)node * 64 + (q & 15) * 4] = u;
    }
}

// ---------- pull aggregation over pre-scaled bf16 rows ----------
// out[i] = dinv[i] * ( sum_{s in N(i)} Xs[s] + Xs[i] ) + bias
// wave = 1 node; slot e = lane>>4 handles edges j+4e..j+4e+3; c = lane&15 -> features 4c..4c+3.
// Single fully-masked 16-edge loop: invalid lanes gather the zeroed pad row at Xs[-64].
template<int OUTBF>
__global__ __launch_bounds__(256) void agg_bf16(const unsigned short* __restrict__ Xs,
                                                const float* __restrict__ dinv,
                                                const int* __restrict__ row_start,
                                                const int* __restrict__ sorted_src,
                                                const float* __restrict__ bias,
                                                void* __restrict__ outp, int n) {
    int lane = threadIdx.x & 63;
    int wid = threadIdx.x >> 6;
    int wave = blockIdx.x * (blockDim.x >> 6) + wid;
    int nwaves = gridDim.x * (blockDim.x >> 6);
    int e = lane >> 4;
    int c = lane & 15;
    const int ZOFF = -64;   // element offset of the zeroed pad row
    for (int i = wave; i < n; i += nwaves) {
        int s0 = row_start[i], s1 = row_start[i + 1];
        float di = dinv[i];
        ushort4 uself = *(const ushort4*)&Xs[(size_t)i * NF + 4 * c];
        float a0 = 0.f, a1 = 0.f, a2 = 0.f, a3 = 0.f;
        float g0 = 0.f, g1 = 0.f, g2 = 0.f, g3 = 0.f;
        for (int j = s0; j < s1; j += 16) {
            int b0 = j + 4 * e;
            int sj0 = b0, sj1 = b0 + 1, sj2 = b0 + 2, sj3 = b0 + 3;
            int i0 = sorted_src[min(sj0, s1 - 1)];
            int i1 = sorted_src[min(sj1, s1 - 1)];
            int i2 = sorted_src[min(sj2, s1 - 1)];
            int i3 = sorted_src[min(sj3, s1 - 1)];
            int o0 = (sj0 < s1) ? (i0 << 6) : ZOFF;
            int o1 = (sj1 < s1) ? (i1 << 6) : ZOFF;
            int o2 = (sj2 < s1) ? (i2 << 6) : ZOFF;
            int o3 = (sj3 < s1) ? (i3 << 6) : ZOFF;
            ushort4 u0 = *(const ushort4*)(Xs + o0 + 4 * c);
            ushort4 u1 = *(const ushort4*)(Xs + o1 + 4 * c);
            ushort4 u2 = *(const ushort4*)(Xs + o2 + 4 * c);
            ushort4 u3 = *(const ushort4*)(Xs + o3 + 4 * c);
            a0 += bf2f(u0.x); a1 += bf2f(u0.y); a2 += bf2f(u0.z); a3 += bf2f(u0.w);
            g0 += bf2f(u1.x); g1 += bf2f(u1.y); g2 += bf2f(u1.z); g3 += bf2f(u1.w);
            a0 += bf2f(u2.x); a1 += bf2f(u2.y); a2 += bf2f(u2.z); a3 += bf2f(u2.w);
            g0 += bf2f(u3.x); g1 += bf2f(u3.y); g2 += bf2f(u3.z); g3 += bf2f(u3.w);
        }
        a0 += g0; a1 += g1; a2 += g2; a3 += g3;
        a0 += __shfl_xor(a0, 16, 64); a1 += __shfl_xor(a1, 16, 64);
        a2 += __shfl_xor(a2, 16, 64); a3 += __shfl_xor(a3, 16, 64);
        a0 += __shfl_xor(a0, 32, 64); a1 += __shfl_xor(a1, 32, 64);
        a2 += __shfl_xor(a2, 32, 64); a3 += __shfl_xor(a3, 32, 64);
        if (e == 0) {
            a0 = di * (a0 + bf2f(uself.x));
            a1 = di * (a1 + bf2f(uself.y));
            a2 = di * (a2 + bf2f(uself.z));
            a3 = di * (a3 + bf2f(uself.w));
            if (bias) {
                float4 bb = *(const float4*)&bias[4 * c];
                a0 += bb.x; a1 += bb.y; a2 += bb.z; a3 += bb.w;
            }
            if constexpr (OUTBF) {
                unsigned short* out = (unsigned short*)outp;
                ushort4 o;
                o.x = f2bf(a0); o.y = f2bf(a1); o.z = f2bf(a2); o.w = f2bf(a3);
                *(ushort4*)&out[(size_t)i * NF + 4 * c] = o;
            } else {
                float* out = (float*)outp;
                float4 o; o.x = a0; o.y = a1; o.z = a2; o.w = a3;
                *(float4*)&out[(size_t)i * NF + 4 * c] = o;
            }
        }
    }
}

// ---------- MFMA fused GEMM: Tbf = bf16( dinv[row] * (relu(A@W1+b1) @ W2) ) ----------
__global__ __launch_bounds__(256) void gemm_mfma(const unsigned short* __restrict__ Abf,
                                                 const unsigned short* __restrict__ W1f,
                                                 const float* __restrict__ b1,
                                                 const unsigned short* __restrict__ W2f,
                                                 const float* __restrict__ dinv,
                                                 unsigned short* __restrict__ Tbf, int n) {
    __shared__ unsigned short h_all[4][16 * 136];
    const int t = threadIdx.x;
    const int wid = t >> 6, lane = t & 63;
    const int m = lane & 15, kg = lane >> 4;
    const int wrow = blockIdx.x * 64 + wid * 16;
    unsigned short* h_lds = h_all[wid];

    int arow = wrow + m; if (arow >= n) arow = n - 1;
    bf16x8 a0 = *(const bf16x8*)&Abf[(size_t)arow * 64 + kg * 8];
    bf16x8 a1 = *(const bf16x8*)&Abf[(size_t)arow * 64 + 32 + kg * 8];

    #pragma unroll
    for (int ct = 0; ct < 8; ++ct) {
        f32x4 acc = {0.f, 0.f, 0.f, 0.f};
        bf16x8 w0 = *(const bf16x8*)&W1f[(ct * 2 + 0) * 512 + lane * 8];
        bf16x8 w1 = *(const bf16x8*)&W1f[(ct * 2 + 1) * 512 + lane * 8];
        acc = __builtin_amdgcn_mfma_f32_16x16x32_bf16(a0, w0, acc, 0, 0, 0);
        acc = __builtin_amdgcn_mfma_f32_16x16x32_bf16(a1, w1, acc, 0, 0, 0);
        float bb = b1[ct * 16 + m];
        #pragma unroll
        for (int r = 0; r < 4; ++r) {
            float v = fmaxf(acc[r] + bb, 0.f);
            h_lds[(kg * 4 + r) * 136 + ct * 16 + m] = f2bf(v);
        }
    }

    bf16x8 hf[4];
    #pragma unroll
    for (int ks = 0; ks < 4; ++ks)
        hf[ks] = *(const bf16x8*)&h_lds[m * 136 + ks * 32 + kg * 8];

    float dv[4];
    #pragma unroll
    for (int r = 0; r < 4; ++r) {
        int row = wrow + kg * 4 + r;
        dv[r] = (row < n) ? dinv[row] : 0.f;
    }
    #pragma unroll
    for (int ct = 0; ct < 4; ++ct) {
        f32x4 acc = {0.f, 0.f, 0.f, 0.f};
        #pragma unroll
        for (int ks = 0; ks < 4; ++ks) {
            bf16x8 w = *(const bf16x8*)&W2f[(ct * 4 + ks) * 512 + lane * 8];
            acc = __builtin_amdgcn_mfma_f32_16x16x32_bf16(hf[ks], w, acc, 0, 0, 0);
        }
        #pragma unroll
        for (int r = 0; r < 4; ++r) {
            int row = wrow + kg * 4 + r;
            if (row < n) Tbf[(size_t)row * 64 + ct * 16 + m] = f2bf(acc[r] * dv[r]);
        }
    }
}

extern "C" void kernel_launch(void* const* d_in, const int* in_sizes, int n_in,
                              void* d_out, int out_size, void* d_ws, size_t ws_size,
                              hipStream_t stream) {
    const int* edge = (const int*)d_in[0];       // int32 (JAX x64 disabled)
    const float* emb = (const float*)d_in[1];
    const float* W1  = (const float*)d_in[2];
    const float* b1  = (const float*)d_in[3];
    const float* W2  = (const float*)d_in[4];
    const float* b2  = (const float*)d_in[5];
    int E = in_sizes[0] / 2;
    const int* src = edge;
    const int* dst = edge + E;
    int n = N_NODES_C;
    int nbin = (E + CHUNK - 1) / CHUNK;

    char* p = (char*)d_ws;
    int*   row_start  = (int*)p;   p += align256((size_t)(n + 1) * 4);
    float* dinv       = (float*)p; p += align256((size_t)n * 4);
    int*   base196    = (int*)p;   p += align256(256 * 4);
    int*   colsum     = (int*)p;   p += align256(256 * 4);
    int*   done_ctr   = (int*)p;   p += align256(4);
    int*   chunk_hist = (int*)p;   p += align256((size_t)nbin * NB * 4);
    int*   gpart      = (int*)p;   p += align256((size_t)nbin * NB * 4);
    unsigned short* W1f = (unsigned short*)p; p += align256(8192 * 2);
    unsigned short* W2f = (unsigned short*)p; p += align256(8192 * 2);
    int*   sorted_src = (int*)p;   p += align256((size_t)E * 4);
    int*   zpadA      = (int*)p;   p += 256;   // zero pad row for Abf
    unsigned short* Abf = (unsigned short*)p; p += align256((size_t)n * NF * 2);
    int*   zpadX      = (int*)p;   p += 256;   // zero pad row for Xs
    unsigned short* Xs  = (unsigned short*)p; p += align256((size_t)n * NF * 2);
    // packed aliases Abf: its lifetime [bin_kernel2, bucket_sort_deg] ends before Abf is written
    int* packed = (int*)Abf;

    // pass A: per-chunk histograms (+ weight prep, + done_ctr reset)
    count_hist<<<nbin, 1024, 0, stream>>>(dst, E, chunk_hist, W1, W2, W1f, W2f, done_ctr);
    // cross-chunk scans (+ tail-block 196-scan, row_start[n], pad zeroing)
    scan_cols<<<NB, 64, 0, stream>>>(chunk_hist, nbin, gpart, colsum,
                                     base196, row_start, n, zpadA, zpadX, done_ctr);
    // deterministic bucket binning
    bin_kernel2<<<nbin, 1024, 0, stream>>>(src, dst, E, chunk_hist, gpart, base196, packed);
    // per-bucket sort + degrees + dinv (+ fused emb prescale into Xs)
    bucket_sort_deg<<<NB, 1024, 0, stream>>>(base196, packed, sorted_src, row_start, dinv,
                                             emb, Xs, n);
    // layer 1 aggregation -> Abf (bf16)
    agg_bf16<1><<<4096, 256, 0, stream>>>(Xs, dinv, row_start, sorted_src, nullptr, Abf, n);
    // fused MFMA GEMM: Xs <- bf16( dinv * (relu(Abf@W1+b1)@W2) )
    gemm_mfma<<<(n + 63) / 64, 256, 0, stream>>>(Abf, W1f, b1, W2f, dinv, Xs, n);
    // layer 2 aggregation + b2 -> out (f32)
    agg_bf16<0><<<4096, 256, 0, stream>>>(Xs, dinv, row_start, sorted_src, b2, d_out, n);
}